// Round 1
// baseline (1622.569 us; speedup 1.0000x reference)
//
#include <hip/hip_runtime.h>
#include <hip/hip_bf16.h>

typedef __attribute__((ext_vector_type(8))) short  bf16x8;
typedef __attribute__((ext_vector_type(4))) short  s16x4;
typedef __attribute__((ext_vector_type(4))) float  f32x4;

#define LOG2E 1.44269504088896340736f

__device__ __forceinline__ unsigned short f2bf(float x) {
    union { float f; unsigned int u; } v; v.f = x;
    unsigned int u = v.u;
    u += 0x7fffu + ((u >> 16) & 1u);          // round-to-nearest-even
    return (unsigned short)(u >> 16);
}

__device__ __forceinline__ float fast_sigmoid(float x) {
    float e = __builtin_amdgcn_exp2f(-LOG2E * x);
    return __builtin_amdgcn_rcpf(1.0f + e);
}
__device__ __forceinline__ float fast_tanh(float x) {
    float e = __builtin_amdgcn_exp2f(2.0f * LOG2E * x);
    return 1.0f - 2.0f * __builtin_amdgcn_rcpf(1.0f + e);
}

// ---------------------------------------------------------------------------
// Pack a [1024 x 256] fp32 weight into bf16 MFMA-B-fragment-major layout:
//   frag id fid = w*64 + kk*8 + j   (wave w 0..7, kstep kk 0..7, tile j=g*2+tn)
//   record: dst[(fid*64 + lane)*8 + e] = bf16( W[R][k] )
//   R = g*256 + w*32 + tn*16 + (lane&15)
//   k = kk*32 + 4*(lane>>4) + (e&3) + 16*(e>>2)
// ---------------------------------------------------------------------------
__global__ void pack_w_big(const float* __restrict__ W, unsigned short* __restrict__ dst) {
    int idx  = blockIdx.x * 256 + threadIdx.x;   // 0..32767
    int lane = idx & 63;
    int fid  = idx >> 6;                         // 0..511
    int j    = fid & 7;
    int kk   = (fid >> 3) & 7;
    int w    = fid >> 6;
    int g    = j >> 1, tn = j & 1;
    int R    = g * 256 + w * 32 + tn * 16 + (lane & 15);
    int kb   = kk * 32 + 4 * (lane >> 4);
    const float* src = W + (size_t)R * 256 + kb;
    union { unsigned short s[8]; uint4 v; } u;
#pragma unroll
    for (int e = 0; e < 8; ++e) {
        int k = (e & 3) + 16 * (e >> 2);
        u.s[e] = f2bf(src[k]);
    }
    *(uint4*)(dst + (size_t)idx * 8) = u.v;
}

// Same for W_out [128 x 256]: fid = wv*8 + kk, R = wv*16 + (lane&15)
__global__ void pack_w_out(const float* __restrict__ W, unsigned short* __restrict__ dst) {
    int idx  = blockIdx.x * 256 + threadIdx.x;   // 0..4095
    int lane = idx & 63;
    int fid  = idx >> 6;                         // 0..63
    int kk   = fid & 7;
    int wv   = fid >> 3;
    int R    = wv * 16 + (lane & 15);
    int kb   = kk * 32 + 4 * (lane >> 4);
    const float* src = W + (size_t)R * 256 + kb;
    union { unsigned short s[8]; uint4 v; } u;
#pragma unroll
    for (int e = 0; e < 8; ++e) {
        int k = (e & 3) + 16 * (e >> 2);
        u.s[e] = f2bf(src[k]);
    }
    *(uint4*)(dst + (size_t)idx * 8) = u.v;
}

// ---------------------------------------------------------------------------
// Persistent LSTM kernel. Grid = B/16 blocks x 512 threads (8 waves).
// Wave w owns hidden strip [w*32, w*32+32) of gates/h/c and out cols [w*16,+16).
// h lives in LDS (bf16, double buffered, XOR-swizzled), c in VGPRs.
// ---------------------------------------------------------------------------
__global__ __launch_bounds__(512, 2) void lstm_main(
    const float* __restrict__ C,
    const unsigned short* __restrict__ Wih_p,
    const unsigned short* __restrict__ Whh_p,
    const unsigned short* __restrict__ Wout_p,
    const float* __restrict__ b_ih,
    const float* __restrict__ b_hh,
    const float* __restrict__ b_out,
    float* __restrict__ Y,
    int T, int Btot)
{
    __shared__ short hbuf[2][16 * 256];
    const int tid  = threadIdx.x;
    const int l    = tid & 63;
    const int wid  = tid >> 6;     // 0..7
    const int l15  = l & 15;
    const int g4   = l >> 4;       // 0..3
    const int row0 = blockIdx.x * 16;

    // ---- stage C tile -> hbuf[0] (bf16, swizzled at 8B-slot granularity) ----
    {
        int r  = tid >> 5;         // 0..15
        int cb = tid & 31;         // 8-col block
        const float* src = C + (size_t)(row0 + r) * 256 + cb * 8;
        float4 f0 = *(const float4*)(src);
        float4 f1 = *(const float4*)(src + 4);
        int m  = 9 * (r & 7);
        int s0 = cb * 2;
        short* hb = hbuf[0] + r * 256;
        union { unsigned short s[4]; unsigned long long v; } p0, p1;
        p0.s[0] = f2bf(f0.x); p0.s[1] = f2bf(f0.y); p0.s[2] = f2bf(f0.z); p0.s[3] = f2bf(f0.w);
        p1.s[0] = f2bf(f1.x); p1.s[1] = f2bf(f1.y); p1.s[2] = f2bf(f1.z); p1.s[3] = f2bf(f1.w);
        *(unsigned long long*)(hb + ((s0 ^ m) * 4))       = p0.v;
        *(unsigned long long*)(hb + (((s0 + 1) ^ m) * 4)) = p1.v;
    }
    __syncthreads();

    // A-fragment loader: h[16 rows x 256], lane l -> row=l&15,
    // k = kk*32 + 4*(l>>4) + {0..3} and +16 (two stacked K=16 halves)
    const int msw = 9 * (l15 & 7);
    auto loadA = [&](const short* buf, int kk) -> bf16x8 {
        int slo = kk * 8 + g4;
        const short* base = buf + l15 * 256;
        s16x4 lo = *(const s16x4*)(base + ((slo ^ msw) * 4));
        s16x4 hi = *(const s16x4*)(base + (((slo + 4) ^ msw) * 4));
        bf16x8 a;
        a[0] = lo[0]; a[1] = lo[1]; a[2] = lo[2]; a[3] = lo[3];
        a[4] = hi[0]; a[5] = hi[1]; a[6] = hi[2]; a[7] = hi[3];
        return a;
    };

    // W_out fragments: register resident for whole kernel
    bf16x8 wout[8];
#pragma unroll
    for (int kk = 0; kk < 8; ++kk)
        wout[kk] = *(const bf16x8*)(Wout_p + ((size_t)(wid * 8 + kk) * 64 + l) * 8);

    const unsigned short* wib = Wih_p + (size_t)wid * 32768;
    const unsigned short* whb = Whh_p + (size_t)wid * 32768;

    // ---- x_gates = C @ W_ih^T + b_ih + b_hh (held in registers) ----
    f32x4 acc[8];
#pragma unroll
    for (int j = 0; j < 8; ++j) acc[j] = (f32x4){0.f, 0.f, 0.f, 0.f};
#pragma unroll
    for (int kk = 0; kk < 8; ++kk) {
        bf16x8 a = loadA(hbuf[0], kk);
#pragma unroll
        for (int j = 0; j < 8; ++j) {
            bf16x8 b = *(const bf16x8*)(wib + ((kk * 8 + j) * 64 + l) * 8);
            acc[j] = __builtin_amdgcn_mfma_f32_16x16x32_bf16(a, b, acc[j], 0, 0, 0);
        }
    }
    f32x4 xg[8];
#pragma unroll
    for (int j = 0; j < 8; ++j) {
        int g = j >> 1, tn = j & 1;
        int col = g * 256 + wid * 32 + tn * 16 + l15;
        float bias = b_ih[col] + b_hh[col];
        xg[j] = acc[j] + bias;
    }

    float cst[8];
#pragma unroll
    for (int i = 0; i < 8; ++i) cst[i] = 0.f;
    const float by = b_out[wid * 16 + l15];

    // cell update + h write (swizzled bf16 scatter into nxt buffer)
    auto update_write = [&](short* nxtb) {
#pragma unroll
        for (int tn = 0; tn < 2; ++tn) {
#pragma unroll
            for (int r = 0; r < 4; ++r) {
                float iv = fast_sigmoid(acc[0 + tn][r]);
                float fv = fast_sigmoid(acc[2 + tn][r]);
                float gv = fast_tanh(acc[4 + tn][r]);
                float ov = fast_sigmoid(acc[6 + tn][r]);
                float cn = fv * cst[tn * 4 + r] + iv * gv;
                cst[tn * 4 + r] = cn;
                float hn = ov * fast_tanh(cn);
                int row = 4 * g4 + r;
                int col = wid * 32 + tn * 16 + l15;
                int ps  = (col >> 2) ^ (9 * (row & 7));
                nxtb[row * 256 + ps * 4 + (col & 3)] = (short)f2bf(hn);
            }
        }
    };

    // ---- t = 0: gates = x_gates (h0 = 0) ----
#pragma unroll
    for (int j = 0; j < 8; ++j) acc[j] = xg[j];
    update_write(hbuf[1]);
    __syncthreads();

    // ---- steps t = 1..T-1: fused [gates GEMM for t] + [y GEMM for t-1] ----
    for (int t = 1; t < T; ++t) {
        const short* curb = hbuf[t & 1];
        short*       nxtb = hbuf[(t + 1) & 1];
        f32x4 accy = (f32x4){by, by, by, by};
#pragma unroll
        for (int j = 0; j < 8; ++j) acc[j] = xg[j];
#pragma unroll
        for (int kk = 0; kk < 8; ++kk) {
            bf16x8 a = loadA(curb, kk);
            accy = __builtin_amdgcn_mfma_f32_16x16x32_bf16(a, wout[kk], accy, 0, 0, 0);
#pragma unroll
            for (int j = 0; j < 8; ++j) {
                bf16x8 b = *(const bf16x8*)(whb + ((kk * 8 + j) * 64 + l) * 8);
                acc[j] = __builtin_amdgcn_mfma_f32_16x16x32_bf16(a, b, acc[j], 0, 0, 0);
            }
        }
        // store y_{t-1} = h_t @ W_out^T + b_out
        {
            float* yp = Y + ((size_t)(t - 1) * Btot + row0 + 4 * g4) * 128 + wid * 16 + l15;
#pragma unroll
            for (int r = 0; r < 4; ++r) yp[(size_t)r * 128] = accy[r];
        }
        update_write(nxtb);
        __syncthreads();
    }

    // ---- epilogue: y_{T-1} = h_T @ W_out^T + b_out ----
    {
        const short* curb = hbuf[T & 1];
        f32x4 accy = (f32x4){by, by, by, by};
#pragma unroll
        for (int kk = 0; kk < 8; ++kk) {
            bf16x8 a = loadA(curb, kk);
            accy = __builtin_amdgcn_mfma_f32_16x16x32_bf16(a, wout[kk], accy, 0, 0, 0);
        }
        float* yp = Y + ((size_t)(T - 1) * Btot + row0 + 4 * g4) * 128 + wid * 16 + l15;
#pragma unroll
        for (int r = 0; r < 4; ++r) yp[(size_t)r * 128] = accy[r];
    }
}

extern "C" void kernel_launch(void* const* d_in, const int* in_sizes, int n_in,
                              void* d_out, int out_size, void* d_ws, size_t ws_size,
                              hipStream_t stream) {
    const float* C     = (const float*)d_in[0];
    const float* W_ih  = (const float*)d_in[1];
    const float* W_hh  = (const float*)d_in[2];
    const float* b_ih  = (const float*)d_in[3];
    const float* b_hh  = (const float*)d_in[4];
    const float* W_out = (const float*)d_in[5];
    const float* b_out = (const float*)d_in[6];

    const int H    = 256;                 // in_sizes[1] = 4H*H = 262144
    const int Btot = in_sizes[0] / H;     // 2048
    const int O    = in_sizes[5] / H;     // 128
    const int T    = out_size / (Btot * O);

    unsigned short* Whh_p  = (unsigned short*)d_ws;          // 512 KB
    unsigned short* Wih_p  = Whh_p + (1 << 18);              // 512 KB
    unsigned short* Wout_p = Wih_p + (1 << 18);              // 64 KB

    hipLaunchKernelGGL(pack_w_big, dim3(128), dim3(256), 0, stream, W_hh, Whh_p);
    hipLaunchKernelGGL(pack_w_big, dim3(128), dim3(256), 0, stream, W_ih, Wih_p);
    hipLaunchKernelGGL(pack_w_out, dim3(16),  dim3(256), 0, stream, W_out, Wout_p);
    hipLaunchKernelGGL(lstm_main, dim3(Btot / 16), dim3(512), 0, stream,
                       C, Wih_p, Whh_p, Wout_p, b_ih, b_hh, b_out,
                       (float*)d_out, T, Btot);
}

// Round 2
// 743.057 us; speedup vs baseline: 2.1836x; 2.1836x over previous
//
#include <hip/hip_runtime.h>
#include <hip/hip_bf16.h>

typedef __attribute__((ext_vector_type(8))) short  bf16x8;
typedef __attribute__((ext_vector_type(4))) short  s16x4;
typedef __attribute__((ext_vector_type(4))) float  f32x4;

#define LOG2E 1.44269504088896340736f

template<int N> struct ic { static constexpr int v = N; };

__device__ __forceinline__ unsigned short f2bf(float x) {
    union { float f; unsigned int u; } v; v.f = x;
    unsigned int u = v.u;
    u += 0x7fffu + ((u >> 16) & 1u);          // round-to-nearest-even
    return (unsigned short)(u >> 16);
}

__device__ __forceinline__ float fast_sigmoid(float x) {
    float e = __builtin_amdgcn_exp2f(-LOG2E * x);
    return __builtin_amdgcn_rcpf(1.0f + e);
}
__device__ __forceinline__ float fast_tanh(float x) {
    float e = __builtin_amdgcn_exp2f(2.0f * LOG2E * x);
    return 1.0f - 2.0f * __builtin_amdgcn_rcpf(1.0f + e);
}

// ---------------------------------------------------------------------------
// Pack [1024 x 256] fp32 weight into bf16 MFMA-B-fragment-major layout.
//   fid = w*64 + kk*8 + j ; dst[(fid*64+lane)*8+e] = bf16(W[R][k])
//   R = g*256 + w*32 + tn*16 + (lane&15), j = g*2+tn
//   k = kk*32 + 4*(lane>>4) + (e&3) + 16*(e>>2)
// ---------------------------------------------------------------------------
__global__ void pack_w_big(const float* __restrict__ W, unsigned short* __restrict__ dst) {
    int idx  = blockIdx.x * 256 + threadIdx.x;   // 0..32767
    int lane = idx & 63;
    int fid  = idx >> 6;                         // 0..511
    int j    = fid & 7;
    int kk   = (fid >> 3) & 7;
    int w    = fid >> 6;
    int g    = j >> 1, tn = j & 1;
    int R    = g * 256 + w * 32 + tn * 16 + (lane & 15);
    int kb   = kk * 32 + 4 * (lane >> 4);
    const float* src = W + (size_t)R * 256 + kb;
    union { unsigned short s[8]; uint4 v; } u;
#pragma unroll
    for (int e = 0; e < 8; ++e) {
        int k = (e & 3) + 16 * (e >> 2);
        u.s[e] = f2bf(src[k]);
    }
    *(uint4*)(dst + (size_t)idx * 8) = u.v;
}

// W_out [128 x 256]: fid = wv*8 + kk, R = wv*16 + (lane&15)
__global__ void pack_w_out(const float* __restrict__ W, unsigned short* __restrict__ dst) {
    int idx  = blockIdx.x * 256 + threadIdx.x;   // 0..4095
    int lane = idx & 63;
    int fid  = idx >> 6;                         // 0..63
    int kk   = fid & 7;
    int wv   = fid >> 3;
    int R    = wv * 16 + (lane & 15);
    int kb   = kk * 32 + 4 * (lane >> 4);
    const float* src = W + (size_t)R * 256 + kb;
    union { unsigned short s[8]; uint4 v; } u;
#pragma unroll
    for (int e = 0; e < 8; ++e) {
        int k = (e & 3) + 16 * (e >> 2);
        u.s[e] = f2bf(src[k]);
    }
    *(uint4*)(dst + (size_t)idx * 8) = u.v;
}

// ---------------------------------------------------------------------------
// Persistent LSTM. 128 blocks x 512 thr (8 waves). Wave w owns gate strip
// [w*32,w*32+32) x {i,f,g,o} and y cols [w*16,+16). h: LDS dbuf (swizzled
// bf16). Whh kk0/kk1 fragments parked in LDS (128 KB); kk2..7 streamed from
// L2 through a depth-2 register double-buffer with cross-step wraparound.
// ---------------------------------------------------------------------------
__global__ __launch_bounds__(512, 2) void lstm_main(
    const float* __restrict__ C,
    const unsigned short* __restrict__ Wih_p,
    const unsigned short* __restrict__ Whh_p,
    const unsigned short* __restrict__ Wout_p,
    const float* __restrict__ b_ih,
    const float* __restrict__ b_hh,
    const float* __restrict__ b_out,
    float* __restrict__ Y,
    int T, int Btot)
{
    __shared__ short hbuf[2][16 * 256];     // 16 KB
    __shared__ short wpark[8][8192];        // 128 KB: per-wave kk0,kk1 B-frags

    const int tid  = threadIdx.x;
    const int l    = tid & 63;
    const int wid  = tid >> 6;     // 0..7
    const int l15  = l & 15;
    const int g4   = l >> 4;       // 0..3
    const int row0 = blockIdx.x * 16;

    const unsigned short* wib = Wih_p + (size_t)wid * 32768;
    const unsigned short* whb = Whh_p + (size_t)wid * 32768;

    // ---- stage C tile -> hbuf[0] (bf16, swizzled 8B slots) ----
    {
        int r  = tid >> 5;         // 0..15
        int cb = tid & 31;         // 8-col block
        const float* src = C + (size_t)(row0 + r) * 256 + cb * 8;
        float4 f0 = *(const float4*)(src);
        float4 f1 = *(const float4*)(src + 4);
        int m  = 9 * (r & 7);
        int s0 = cb * 2;
        short* hb = hbuf[0] + r * 256;
        union { unsigned short s[4]; unsigned long long v; } p0, p1;
        p0.s[0] = f2bf(f0.x); p0.s[1] = f2bf(f0.y); p0.s[2] = f2bf(f0.z); p0.s[3] = f2bf(f0.w);
        p1.s[0] = f2bf(f1.x); p1.s[1] = f2bf(f1.y); p1.s[2] = f2bf(f1.z); p1.s[3] = f2bf(f1.w);
        *(unsigned long long*)(hb + ((s0 ^ m) * 4))       = p0.v;
        *(unsigned long long*)(hb + (((s0 + 1) ^ m) * 4)) = p1.v;
    }

    // ---- park Whh kk0,kk1 fragments into LDS (wave-private region) ----
    {
        bf16x8 tmp[16];
#pragma unroll
        for (int f = 0; f < 16; ++f)
            tmp[f] = *(const bf16x8*)(whb + ((size_t)f * 64 + l) * 8);
#pragma unroll
        for (int f = 0; f < 16; ++f)
            *(bf16x8*)&wpark[wid][(f * 64 + l) * 8] = tmp[f];
    }
    __syncthreads();

    // A-frag loader (h tile): row = l&15, k = kk*32 + 4*(l>>4) + {0..3,16..19}
    const int msw = 9 * (l15 & 7);
    auto loadA = [&](const short* buf, int kk) -> bf16x8 {
        int slo = kk * 8 + g4;
        const short* base = buf + l15 * 256;
        s16x4 lo = *(const s16x4*)(base + ((slo ^ msw) * 4));
        s16x4 hi = *(const s16x4*)(base + (((slo + 4) ^ msw) * 4));
        bf16x8 a;
        a[0] = lo[0]; a[1] = lo[1]; a[2] = lo[2]; a[3] = lo[3];
        a[4] = hi[0]; a[5] = hi[1]; a[6] = hi[2]; a[7] = hi[3];
        return a;
    };
    auto loadB = [&](const unsigned short* wb, int kk, int j) -> bf16x8 {
        return *(const bf16x8*)(wb + (((size_t)kk * 8 + j) * 64 + l) * 8);
    };

    // W_out fragments: register resident
    bf16x8 wout[8];
#pragma unroll
    for (int kk = 0; kk < 8; ++kk)
        wout[kk] = *(const bf16x8*)(Wout_p + ((size_t)(wid * 8 + kk) * 64 + l) * 8);

    f32x4 acc[8];
    f32x4 accy;
    bf16x8 b0[8], b1[8];

    // preload streamed double-buffer with Wih kk0,kk1
#pragma unroll
    for (int j = 0; j < 8; ++j) b0[j] = loadB(wib, 0, j);
#pragma unroll
    for (int j = 0; j < 8; ++j) b1[j] = loadB(wib, 1, j);

#pragma unroll
    for (int j = 0; j < 8; ++j) acc[j] = (f32x4){0.f, 0.f, 0.f, 0.f};

    // ---- x_gates GEMM (streamed, pipelined; hands b0/b1 off to Whh kk2/kk3)
    auto xg_kk = [&](auto kkc, bf16x8 (&bb)[8], const unsigned short* nwb, auto nxtc) {
        constexpr int kk = decltype(kkc)::v;
        constexpr int nx = decltype(nxtc)::v;
        bf16x8 a = loadA(hbuf[0], kk);
#pragma unroll
        for (int j = 0; j < 8; ++j)
            acc[j] = __builtin_amdgcn_mfma_f32_16x16x32_bf16(a, bb[j], acc[j], 0, 0, 0);
#pragma unroll
        for (int j = 0; j < 8; ++j) bb[j] = loadB(nwb, nx, j);
    };
    xg_kk(ic<0>{}, b0, wib, ic<2>{});
    xg_kk(ic<1>{}, b1, wib, ic<3>{});
    xg_kk(ic<2>{}, b0, wib, ic<4>{});
    xg_kk(ic<3>{}, b1, wib, ic<5>{});
    xg_kk(ic<4>{}, b0, wib, ic<6>{});
    xg_kk(ic<5>{}, b1, wib, ic<7>{});
    xg_kk(ic<6>{}, b0, whb, ic<2>{});   // handoff: next step needs Whh kk2
    xg_kk(ic<7>{}, b1, whb, ic<3>{});   // handoff: Whh kk3

    f32x4 xg[8];
#pragma unroll
    for (int j = 0; j < 8; ++j) {
        int g = j >> 1, tn = j & 1;
        int col = g * 256 + wid * 32 + tn * 16 + l15;
        xg[j] = acc[j] + (b_ih[col] + b_hh[col]);
    }

    float cst[8];
#pragma unroll
    for (int i = 0; i < 8; ++i) cst[i] = 0.f;
    const float by = b_out[wid * 16 + l15];

    auto update_write = [&](short* nxtb) {
#pragma unroll
        for (int tn = 0; tn < 2; ++tn) {
#pragma unroll
            for (int r = 0; r < 4; ++r) {
                float iv = fast_sigmoid(acc[0 + tn][r]);
                float fv = fast_sigmoid(acc[2 + tn][r]);
                float gv = fast_tanh(acc[4 + tn][r]);
                float ov = fast_sigmoid(acc[6 + tn][r]);
                float cn = fv * cst[tn * 4 + r] + iv * gv;
                cst[tn * 4 + r] = cn;
                float hn = ov * fast_tanh(cn);
                int row = 4 * g4 + r;
                int col = wid * 32 + tn * 16 + l15;
                int ps  = (col >> 2) ^ (9 * (row & 7));
                nxtb[row * 256 + ps * 4 + (col & 3)] = (short)f2bf(hn);
            }
        }
    };

    // ---- t = 0: gates = x_gates (h0 = 0) ----
#pragma unroll
    for (int j = 0; j < 8; ++j) acc[j] = xg[j];
    update_write(hbuf[1]);
    __syncthreads();

    auto step_parked = [&](const short* curb, auto kkc) {
        constexpr int kk = decltype(kkc)::v;
        bf16x8 a = loadA(curb, kk);
        accy = __builtin_amdgcn_mfma_f32_16x16x32_bf16(a, wout[kk], accy, 0, 0, 0);
#pragma unroll
        for (int j = 0; j < 8; ++j) {
            bf16x8 b = *(const bf16x8*)&wpark[wid][((kk * 8 + j) * 64 + l) * 8];
            acc[j] = __builtin_amdgcn_mfma_f32_16x16x32_bf16(a, b, acc[j], 0, 0, 0);
        }
    };
    auto step_stream = [&](const short* curb, auto kkc, bf16x8 (&bb)[8], auto nxtc) {
        constexpr int kk = decltype(kkc)::v;
        constexpr int nx = decltype(nxtc)::v;
        bf16x8 a = loadA(curb, kk);
        accy = __builtin_amdgcn_mfma_f32_16x16x32_bf16(a, wout[kk], accy, 0, 0, 0);
#pragma unroll
        for (int j = 0; j < 8; ++j)
            acc[j] = __builtin_amdgcn_mfma_f32_16x16x32_bf16(a, bb[j], acc[j], 0, 0, 0);
#pragma unroll
        for (int j = 0; j < 8; ++j) bb[j] = loadB(whb, nx, j);
    };

    // ---- main loop: fused [gates GEMM t] + [y GEMM t-1] ----
    for (int t = 1; t < T; ++t) {
        const short* curb = hbuf[t & 1];
        short*       nxtb = hbuf[(t + 1) & 1];
        accy = (f32x4){by, by, by, by};
#pragma unroll
        for (int j = 0; j < 8; ++j) acc[j] = xg[j];

        step_parked(curb, ic<0>{});
        step_parked(curb, ic<1>{});
        step_stream(curb, ic<2>{}, b0, ic<4>{});
        step_stream(curb, ic<3>{}, b1, ic<5>{});
        step_stream(curb, ic<4>{}, b0, ic<6>{});
        step_stream(curb, ic<5>{}, b1, ic<7>{});
        step_stream(curb, ic<6>{}, b0, ic<2>{});   // prefetch next step
        step_stream(curb, ic<7>{}, b1, ic<3>{});   // prefetch next step

        // store y_{t-1}
        {
            float* yp = Y + ((size_t)(t - 1) * Btot + row0 + 4 * g4) * 128 + wid * 16 + l15;
#pragma unroll
            for (int r = 0; r < 4; ++r)
                __builtin_nontemporal_store(accy[r], yp + (size_t)r * 128);
        }
        update_write(nxtb);
        __syncthreads();
    }

    // ---- epilogue: y_{T-1} = h_T @ W_out^T + b_out ----
    {
        const short* curb = hbuf[T & 1];
        accy = (f32x4){by, by, by, by};
#pragma unroll
        for (int kk = 0; kk < 8; ++kk) {
            bf16x8 a = loadA(curb, kk);
            accy = __builtin_amdgcn_mfma_f32_16x16x32_bf16(a, wout[kk], accy, 0, 0, 0);
        }
        float* yp = Y + ((size_t)(T - 1) * Btot + row0 + 4 * g4) * 128 + wid * 16 + l15;
#pragma unroll
        for (int r = 0; r < 4; ++r)
            __builtin_nontemporal_store(accy[r], yp + (size_t)r * 128);
    }
}

extern "C" void kernel_launch(void* const* d_in, const int* in_sizes, int n_in,
                              void* d_out, int out_size, void* d_ws, size_t ws_size,
                              hipStream_t stream) {
    const float* C     = (const float*)d_in[0];
    const float* W_ih  = (const float*)d_in[1];
    const float* W_hh  = (const float*)d_in[2];
    const float* b_ih  = (const float*)d_in[3];
    const float* b_hh  = (const float*)d_in[4];
    const float* W_out = (const float*)d_in[5];
    const float* b_out = (const float*)d_in[6];

    const int H    = 256;
    const int Btot = in_sizes[0] / H;     // 2048
    const int O    = in_sizes[5] / H;     // 128
    const int T    = out_size / (Btot * O);

    unsigned short* Whh_p  = (unsigned short*)d_ws;          // 512 KB
    unsigned short* Wih_p  = Whh_p + (1 << 18);              // 512 KB
    unsigned short* Wout_p = Wih_p + (1 << 18);              // 64 KB

    hipLaunchKernelGGL(pack_w_big, dim3(128), dim3(256), 0, stream, W_hh, Whh_p);
    hipLaunchKernelGGL(pack_w_big, dim3(128), dim3(256), 0, stream, W_ih, Wih_p);
    hipLaunchKernelGGL(pack_w_out, dim3(16),  dim3(256), 0, stream, W_out, Wout_p);
    hipLaunchKernelGGL(lstm_main, dim3(Btot / 16), dim3(512), 0, stream,
                       C, Wih_p, Whh_p, Wout_p, b_ih, b_hh, b_out,
                       (float*)d_out, T, Btot);
}